// Round 12
// baseline (3665.758 us; speedup 1.0000x reference)
//
#include <hip/hip_runtime.h>
#include <math.h>

#define NN 512      // nodes
#define NB 256      // batch
#define NT 200      // time steps
#define TPB 256
#define NTEAM 8     // blocks per team (64 cols each)

typedef unsigned long long u64;
typedef _Float16 half8 __attribute__((ext_vector_type(8)));
typedef float f32x4 __attribute__((ext_vector_type(4)));

// ws layout (float offsets)
#define WS_WM  0                        // Wm fp32 [512*512]; k_ode reuses as hbuf ping
#define WS_WC  (NN*NN)                  // Wc = Wm*W2  fp16 [512*512] (halves)
#define WS_C   (WS_WC + NN*NN/2)        // c = b2*Wm^T fp32 [512]
#define WS_H   (WS_C + NN)              // hbuf pong (x0 initially) fp32 [256*512]
#define WS_CNT (WS_H + NB*NN)           // flags: 32 teams x 2 par x 8 blk x 16

// ---- MALL-coherent ops via compiler-generated scoped atomics (no asm) ----
__device__ __forceinline__ void sysst_u64(u64* p, u64 v) {
  __hip_atomic_store(p, v, __ATOMIC_RELAXED, __HIP_MEMORY_SCOPE_SYSTEM);
}
__device__ __forceinline__ u64 sysld_u64(const u64* p) {
  return __hip_atomic_load(p, __ATOMIC_RELAXED, __HIP_MEMORY_SCOPE_SYSTEM);
}
__device__ __forceinline__ void sysst_f1(float* p, float v) {
  __hip_atomic_store(p, v, __ATOMIC_RELAXED, __HIP_MEMORY_SCOPE_SYSTEM);
}
__device__ __forceinline__ float sysld_f1(const float* p) {
  return __hip_atomic_load(p, __ATOMIC_RELAXED, __HIP_MEMORY_SCOPE_SYSTEM);
}

__global__ __launch_bounds__(256)
void k_init(const float* __restrict__ W1, const float* __restrict__ mask,
            const float* __restrict__ x_init, float* __restrict__ ws,
            float* __restrict__ out) {
  int gt = blockIdx.x * 256 + threadIdx.x;
  int stride = gridDim.x * 256;
  for (int i = gt; i < NN * NN; i += stride) ws[WS_WM + i] = W1[i] * mask[i];
  for (int i = gt; i < NB * NN / 2; i += stride) {
    u64 q = ((const u64*)x_init)[i];
    int r = i >> 8, np = i & 255;
    *((u64*)(out + (size_t)r * NT * NN) + np) = q;   // traj[:,0,:]
  }
  if (gt < 32 * 2 * NTEAM * 16)
    __hip_atomic_store(((unsigned*)(ws + WS_CNT)) + gt, 0u,
                       __ATOMIC_RELAXED, __HIP_MEMORY_SCOPE_SYSTEM);
}

// One block per node j: Wc[j][:] (fp16), c[j], and x0[:,j] = y0 . Wm[j,:].
__global__ __launch_bounds__(128)
void k_prep(const float* __restrict__ W2g, const float* __restrict__ b2,
            const float* __restrict__ x_init, float* __restrict__ ws) {
  __shared__ float w1row[NN];
  const int j = blockIdx.x;
  const int t = threadIdx.x;
  const float* wm = ws + WS_WM + (size_t)j * NN;
  for (int i = t; i < NN; i += 128) w1row[i] = wm[i];
  __syncthreads();

  f32x4 acc = {0.f, 0.f, 0.f, 0.f};
  for (int m = 0; m < NN; ++m) {
    float w = w1row[m];
    if (w != 0.f)
      acc += w * ((const f32x4*)(W2g + (size_t)m * NN))[t];
  }
  _Float16* wcrow = (_Float16*)(ws + WS_WC) + (size_t)j * NN;
#pragma unroll
  for (int e = 0; e < 4; ++e) wcrow[4 * t + e] = (_Float16)acc[e];

  if (t == 0) {
    float s = 0.f;
    for (int m = 0; m < NN; ++m)
      if (w1row[m] != 0.f) s += b2[m] * w1row[m];
    ws[WS_C + j] = s;
  }

#pragma unroll
  for (int rr = 0; rr < 2; ++rr) {
    int r = t + rr * 128;
    const float* y0 = x_init + (size_t)r * NN;
    float s = 0.f;
    for (int m = 0; m < NN; ++m) {
      float w = w1row[m];
      if (w != 0.f) s = fmaf(y0[m], w, s);
    }
    sysst_f1(ws + WS_H + (size_t)r * NN + j, s);   // x0 -> pong buffer
  }
}

// wait: poll 8 per-block flags (own cacheline each) for >= target, then sync
__device__ __forceinline__ void team_wait(unsigned* flagsp, unsigned target) {
  if (threadIdx.x < NTEAM) {
    while (__hip_atomic_load(flagsp + threadIdx.x * 16, __ATOMIC_RELAXED,
                             __HIP_MEMORY_SCOPE_AGENT) < target)
      __builtin_amdgcn_s_sleep(1);
  }
  __syncthreads();
}
// release: sync (drains each wave's vmcnt -> h stores MALL-visible), then flag
__device__ __forceinline__ void team_release(unsigned* flagsp, int cg, unsigned e) {
  __syncthreads();
  if (threadIdx.x == 0)
    __hip_atomic_store(flagsp + cg * 16, e, __ATOMIC_RELAXED,
                       __HIP_MEMORY_SCOPE_SYSTEM);
}

// Stage 4 rows x 512 fp32 (stride NN) into plane rows p*4..p*4+3 (swizzled).
// 256 threads: one half8 granule each (4 u64 sys loads).
__device__ __forceinline__ void stage4(_Float16* __restrict__ pH,
                                       _Float16* __restrict__ pL,
                                       const float* __restrict__ src,
                                       int p, int tid) {
  const int row = tid >> 6;        // 0..3
  const int g = tid & 63;          // granule
  const u64* s = (const u64*)(src + (size_t)row * NN) + g * 4;
  u64 tmp[4];
#pragma unroll
  for (int i = 0; i < 4; ++i) tmp[i] = sysld_u64(s + i);
  half8 hv, lv;
#pragma unroll
  for (int e = 0; e < 4; ++e) {
    union { u64 q64; float f[2]; } u; u.q64 = tmp[e];
#pragma unroll
    for (int x = 0; x < 2; ++x) {
      float f = u.f[x]; _Float16 h = (_Float16)f;
      hv[e * 2 + x] = h;
      lv[e * 2 + x] = (_Float16)((f - (float)h) * 2048.0f);
    }
  }
  const int dr = p * 4 + row;
  const int idx = dr * 64 + (g ^ dr);
  ((half8*)pH)[idx] = hv;
  ((half8*)pL)[idx] = lv;
}

// Full-K GEMM for this wave's 16x16 tile. A rows 8-15 duplicate rows 0-7.
__device__ __forceinline__ void gemm_tile(const _Float16* yHb, const _Float16* yLb,
                                          const _Float16* wb,
                                          int rc, int kg, int wv, float res[4]) {
  const int swz = rc & 7;
  const half8* pAH = (const half8*)yHb;
  const half8* pAL = (const half8*)yLb;
  const half8* pB  = (const half8*)wb;
  const int abase = (rc & 7) * 64;
  const int bbase = (wv * 16 + rc) * 64;
  f32x4 aH = {0.f, 0.f, 0.f, 0.f};
  f32x4 aL = {0.f, 0.f, 0.f, 0.f};
#pragma unroll
  for (int kt = 0; kt < 16; ++kt) {
    const int gs = (kt * 4 + kg) ^ swz;
    half8 av = pAH[abase + gs];
    half8 al = pAL[abase + gs];
    half8 bv = pB[bbase + gs];
    aH = __builtin_amdgcn_mfma_f32_16x16x32_f16(av, bv, aH, 0, 0, 0);
    aL = __builtin_amdgcn_mfma_f32_16x16x32_f16(al, bv, aL, 0, 0, 0);
  }
#pragma unroll
  for (int r = 0; r < 4; ++r) res[r] = aH[r] + aL[r] * (1.0f / 2048.0f);
}

__global__ __launch_bounds__(TPB, 1)
void k_ode(const float* __restrict__ tspan,
           const float* __restrict__ W2g,
           const float* __restrict__ b1,
           const float* __restrict__ b2,
           float* __restrict__ ws,
           float* __restrict__ out,
           const float* __restrict__ x_init) {
  extern __shared__ _Float16 ldsh[];
  _Float16* wc = ldsh;                 // [64 cols][64 granules] 64KB
  _Float16* w2 = ldsh + 32768;         // 64KB
  _Float16* hH = ldsh + 65536;         // [8 rows][64 granules] 8KB
  _Float16* hL = ldsh + 69632;         // 8KB  -> 144KB total

  const int bid = blockIdx.x;
  const int cg = bid & 7, rg = bid >> 3;
  const int r0 = rg * 8, j0 = cg * 64;
  const int tid = threadIdx.x;
  const int lane = tid & 63, wv = tid >> 6;
  const int rc = lane & 15, kg = lane >> 4;
  const int mycol = j0 + wv * 16 + rc;
  const bool act = (kg < 2);           // lane owns rows r0+kg*4..+3 (parity kg)

  // slot-parity ping-pong: slot q reads hb[q&1], writes hb[(q+1)&1].
  float* hb[2];
  hb[0] = ws + WS_H;                   // pong (x0/h1 initially)
  hb[1] = ws + WS_WM;                  // ping (overlays dead Wm region)
  unsigned* flagsA = ((unsigned*)(ws + WS_CNT)) + rg * (2 * NTEAM * 16);
  unsigned* flagsB = flagsA + NTEAM * 16;

  // --- prologue: Wc (fp16 in ws) and W2 (fp32 global) -> LDS planes ---
  {
    const int col = tid >> 2;          // 0..63
    const int part = tid & 3;          // 0..3, 16 granules each
    const half8* s1 = (const half8*)((const _Float16*)(ws + WS_WC)
                                     + (size_t)(j0 + col) * NN) + part * 16;
    const float* s2 = W2g + (size_t)(j0 + col) * NN + part * 128;
    half8* d1 = (half8*)wc;
    half8* d2 = (half8*)w2;
    const int key = col & 7;
#pragma unroll
    for (int i = 0; i < 16; ++i) {
      int g = part * 16 + i;
      int idx = col * 64 + (g ^ key);
      d1[idx] = s1[i];
      half8 hv;
#pragma unroll
      for (int e = 0; e < 8; ++e) hv[e] = (_Float16)s2[i * 8 + e];
      d2[idx] = hv;
    }
  }
  const float b1s = b1[mycol], b2s = b2[mycol];
  const float c_own = ws[WS_C + mycol];

  // latch register state; compute + store h1(t=0) into hb[0]; flags = 1
  float xb[4], yb[4], H[4];
  if (act) {
#pragma unroll
    for (int r = 0; r < 4; ++r) {
      xb[r] = sysld_f1(hb[0] + (size_t)(r0 + kg * 4 + r) * NN + mycol);
      yb[r] = x_init[(size_t)(r0 + kg * 4 + r) * NN + mycol];
      H[r] = tanhf(xb[r] + b1s);     // h1
      sysst_f1(hb[0] + (size_t)(r0 + kg * 4 + r) * NN + mycol, H[r]);
    }
  }
  __syncthreads();   // drain vmcnt -> h1 MALL-visible
  if (tid == 0) {
    __hip_atomic_store(flagsA + cg * 16, 1u, __ATOMIC_RELAXED,
                       __HIP_MEMORY_SCOPE_SYSTEM);
    __hip_atomic_store(flagsB + cg * 16, 1u, __ATOMIC_RELAXED,
                       __HIP_MEMORY_SCOPE_SYSTEM);
  }

  float res[4], res2[4];

  for (int t = 0; t < NT - 1; ++t) {
    const float dt = tspan[t + 1] - tspan[t];
    const float c6 = dt / 6.0f;
#pragma unroll 1
    for (int s = 0; s < 4; ++s) {
      const int q = t * 4 + s;
      const unsigned target = (unsigned)(q + 1);
      const float* rdb = hb[q & 1];
      float* wrb = hb[(q + 1) & 1];
#pragma unroll
      for (int p = 0; p < 2; ++p) {
        unsigned* fl = p ? flagsB : flagsA;
        team_wait(fl, target);
        stage4(hH, hL, rdb + (size_t)(r0 + p * 4) * NN, p, tid);
        __syncthreads();
        gemm_tile(hH, hL, wc, rc, kg, wv, res);
        if (s == 3) gemm_tile(hH, hL, w2, rc, kg, wv, res2);
        if (kg == p) {
          if (s < 3) {
            const float a = (s == 2) ? dt : dt * 0.5f;
#pragma unroll
            for (int r = 0; r < 4; ++r) {
              float xs = xb[r] + a * (res[r] + c_own);
              float h = tanhf(xs + b1s);
              float st;
              if (s == 2) { H[r] += h;       st = H[r]; }  // exchange H
              else        { H[r] += 2.f * h; st = h;    }  // exchange h
              sysst_f1(wrb + (size_t)(r0 + p * 4 + r) * NN + mycol, st);
            }
          } else {
#pragma unroll
            for (int r = 0; r < 4; ++r) {
              xb[r] += c6 * res[r] + dt * c_own;
              yb[r] += c6 * res2[r] + dt * b2s;
              out[((size_t)(r0 + p * 4 + r) * NT + (t + 1)) * NN + mycol] = yb[r];
              float h = tanhf(xb[r] + b1s);   // h1 of step t+1
              H[r] = h;
              sysst_f1(wrb + (size_t)(r0 + p * 4 + r) * NN + mycol, h);
            }
          }
        }
        team_release(fl, cg, target + 1);
      }
    }
  }
}

extern "C" void kernel_launch(void* const* d_in, const int* in_sizes, int n_in,
                              void* d_out, int out_size, void* d_ws, size_t ws_size,
                              hipStream_t stream) {
  const float* x_init = (const float*)d_in[0];
  const float* tspan  = (const float*)d_in[1];
  const float* W1     = (const float*)d_in[2];
  const float* b1     = (const float*)d_in[3];
  const float* W2     = (const float*)d_in[4];
  const float* b2     = (const float*)d_in[5];
  const float* mask   = (const float*)d_in[6];
  float* out = (float*)d_out;
  float* ws  = (float*)d_ws;

  hipLaunchKernelGGL(k_init, dim3(256), dim3(256), 0, stream,
                     W1, mask, x_init, ws, out);
  hipLaunchKernelGGL(k_prep, dim3(512), dim3(128), 0, stream,
                     W2, b2, x_init, ws);

  const unsigned ldsBytes = 144 * 1024;  // wc 64K + w2 64K + hH 8K + hL 8K
  (void)hipFuncSetAttribute((const void*)k_ode,
                            hipFuncAttributeMaxDynamicSharedMemorySize,
                            (int)ldsBytes);

  // 256 blocks x 144KB LDS = 1 block/CU; all co-resident (proven r6-r10).
  // Two-parity pipeline + slot ping-pong hbuf: writers at slot q touch only
  // the buffer whose slot-q readers have all provably finished (flag >= q+1).
  hipLaunchKernelGGL(k_ode, dim3(256), dim3(TPB), ldsBytes, stream,
                     tspan, W2, b1, b2, ws, out, x_init);
}

// Round 13
// 3105.972 us; speedup vs baseline: 1.1802x; 1.1802x over previous
//
#include <hip/hip_runtime.h>
#include <math.h>

#define NN 512      // nodes
#define NB 256      // batch
#define NT 200      // time steps
#define TPB 256
#define NTEAM 8     // blocks per team (64 cols each)

typedef unsigned long long u64;
typedef _Float16 half8 __attribute__((ext_vector_type(8)));
typedef float f32x4 __attribute__((ext_vector_type(4)));

// ws layout (float offsets)
#define WS_WM  0                        // Wm fp32 [NN*NN]; later hb16[1] overlay
#define WS_WC  (NN*NN)                  // Wc fp16 [NN*NN halves]
#define WS_C   (WS_WC + NN*NN/2)        // c = b2*Wm^T fp32 [NN]
#define WS_X0  (WS_C + NN)              // x0 fp32 [NB*NN]
#define WS_HB0 (WS_X0 + NB*NN)          // hb16[0] fp16 [NB*NN halves]
#define WS_CNT (WS_HB0 + NB*NN/2)       // flags: 32 teams x 8 blk x 16 u32

// ---- MALL-coherent ops via compiler-generated scoped atomics (no asm) ----
__device__ __forceinline__ void sysst_u64(u64* p, u64 v) {
  __hip_atomic_store(p, v, __ATOMIC_RELAXED, __HIP_MEMORY_SCOPE_SYSTEM);
}
__device__ __forceinline__ u64 sysld_u64(const u64* p) {
  return __hip_atomic_load(p, __ATOMIC_RELAXED, __HIP_MEMORY_SCOPE_SYSTEM);
}
__device__ __forceinline__ void sysst_f1(float* p, float v) {
  __hip_atomic_store(p, v, __ATOMIC_RELAXED, __HIP_MEMORY_SCOPE_SYSTEM);
}
__device__ __forceinline__ float sysld_f1(const float* p) {
  return __hip_atomic_load(p, __ATOMIC_RELAXED, __HIP_MEMORY_SCOPE_SYSTEM);
}
__device__ __forceinline__ void sysst_u16(unsigned short* p, unsigned short v) {
  __hip_atomic_store(p, v, __ATOMIC_RELAXED, __HIP_MEMORY_SCOPE_SYSTEM);
}
__device__ __forceinline__ void sysst_h(_Float16* p, float v) {
  union { _Float16 hf; unsigned short us; } cv; cv.hf = (_Float16)v;
  sysst_u16((unsigned short*)p, cv.us);
}

__global__ __launch_bounds__(256)
void k_init(const float* __restrict__ W1, const float* __restrict__ mask,
            const float* __restrict__ x_init, float* __restrict__ ws,
            float* __restrict__ out) {
  int gt = blockIdx.x * 256 + threadIdx.x;
  int stride = gridDim.x * 256;
  for (int i = gt; i < NN * NN; i += stride) ws[WS_WM + i] = W1[i] * mask[i];
  for (int i = gt; i < NB * NN / 2; i += stride) {
    u64 q = ((const u64*)x_init)[i];
    int r = i >> 8, np = i & 255;
    *((u64*)(out + (size_t)r * NT * NN) + np) = q;   // traj[:,0,:]
  }
  if (gt < 32 * NTEAM * 16)
    __hip_atomic_store(((unsigned*)(ws + WS_CNT)) + gt, 0u,
                       __ATOMIC_RELAXED, __HIP_MEMORY_SCOPE_SYSTEM);
}

// One block per node j: Wc[j][:] (fp16), c[j], and x0[:,j] = y0 . Wm[j,:].
__global__ __launch_bounds__(128)
void k_prep(const float* __restrict__ W2g, const float* __restrict__ b2,
            const float* __restrict__ x_init, float* __restrict__ ws) {
  __shared__ float w1row[NN];
  const int j = blockIdx.x;
  const int t = threadIdx.x;
  const float* wm = ws + WS_WM + (size_t)j * NN;
  for (int i = t; i < NN; i += 128) w1row[i] = wm[i];
  __syncthreads();

  f32x4 acc = {0.f, 0.f, 0.f, 0.f};
  for (int m = 0; m < NN; ++m) {
    float w = w1row[m];
    if (w != 0.f)
      acc += w * ((const f32x4*)(W2g + (size_t)m * NN))[t];
  }
  _Float16* wcrow = (_Float16*)(ws + WS_WC) + (size_t)j * NN;
#pragma unroll
  for (int e = 0; e < 4; ++e) wcrow[4 * t + e] = (_Float16)acc[e];

  if (t == 0) {
    float s = 0.f;
    for (int m = 0; m < NN; ++m)
      if (w1row[m] != 0.f) s += b2[m] * w1row[m];
    ws[WS_C + j] = s;
  }

#pragma unroll
  for (int rr = 0; rr < 2; ++rr) {
    int r = t + rr * 128;
    const float* y0 = x_init + (size_t)r * NN;
    float s = 0.f;
    for (int m = 0; m < NN; ++m) {
      float w = w1row[m];
      if (w != 0.f) s = fmaf(y0[m], w, s);
    }
    sysst_f1(ws + WS_X0 + (size_t)r * NN + j, s);
  }
}

// wait: poll 8 per-block flags (own cacheline each) for >= target, then sync
__device__ __forceinline__ void team_wait(unsigned* flagsp, unsigned target) {
  if (threadIdx.x < NTEAM) {
    while (__hip_atomic_load(flagsp + threadIdx.x * 16, __ATOMIC_RELAXED,
                             __HIP_MEMORY_SCOPE_AGENT) < target)
      __builtin_amdgcn_s_sleep(1);
  }
  __syncthreads();
}
// release: sync (drains each wave's vmcnt -> h stores MALL-visible), then flag
__device__ __forceinline__ void team_release(unsigned* flagsp, int cg, unsigned e) {
  __syncthreads();
  if (threadIdx.x == 0)
    __hip_atomic_store(flagsp + cg * 16, e, __ATOMIC_RELAXED,
                       __HIP_MEMORY_SCOPE_SYSTEM);
}

// Stage 8 rows x 512 fp16 (stride NN halves) from MALL -> LDS plane (swz).
// 256 threads: 16 halves each (4 u64 sys loads) = 2 half8 granules.
__device__ __forceinline__ void stage8h(_Float16* __restrict__ plane,
                                        const _Float16* __restrict__ src,
                                        int tid) {
  const int row = tid >> 5;        // 0..7
  const int seg = tid & 31;        // 0..31
  const u64* s = (const u64*)(src + (size_t)row * NN) + seg * 4;
  u64 a0 = sysld_u64(s), a1 = sysld_u64(s + 1);
  u64 a2 = sysld_u64(s + 2), a3 = sysld_u64(s + 3);
  union { u64 q[2]; half8 h; } u0, u1;
  u0.q[0] = a0; u0.q[1] = a1; u1.q[0] = a2; u1.q[1] = a3;
  const int g0 = seg * 2, g1 = seg * 2 + 1;
  ((half8*)plane)[row * 64 + (g0 ^ row)] = u0.h;
  ((half8*)plane)[row * 64 + (g1 ^ row)] = u1.h;
}

// Full-K single-pass GEMM for this wave's 16x16 tile (A rows 8-15 dup 0-7).
__device__ __forceinline__ void gemm8(const _Float16* plane, const _Float16* wb,
                                      int rc, int kg, int wv, float res[4]) {
  const int swz = rc & 7;
  const half8* pA = (const half8*)plane;
  const half8* pB = (const half8*)wb;
  const int abase = (rc & 7) * 64;
  const int bbase = (wv * 16 + rc) * 64;
  f32x4 acc = {0.f, 0.f, 0.f, 0.f};
#pragma unroll
  for (int kt = 0; kt < 16; ++kt) {
    const int gs = (kt * 4 + kg) ^ swz;
    acc = __builtin_amdgcn_mfma_f32_16x16x32_f16(pA[abase + gs], pB[bbase + gs],
                                                 acc, 0, 0, 0);
  }
#pragma unroll
  for (int r = 0; r < 4; ++r) res[r] = acc[r];
}

__global__ __launch_bounds__(TPB, 1)
void k_ode(const float* __restrict__ tspan,
           const float* __restrict__ W2g,
           const float* __restrict__ b1,
           const float* __restrict__ b2,
           float* __restrict__ ws,
           float* __restrict__ out,
           const float* __restrict__ x_init) {
  extern __shared__ _Float16 ldsh[];
  _Float16* wc  = ldsh;                // [64 cols][64 granules] 64KB
  _Float16* w2  = ldsh + 32768;        // 64KB
  _Float16* plA = ldsh + 65536;        // [8 rows][64 granules] 8KB
  _Float16* plB = ldsh + 69632;        // 8KB  -> 144KB total

  const int bid = blockIdx.x;          // 0..127
  const int cg = bid & 7, rgA = bid >> 3;   // rgA 0..15; chain B team rgA+16
  const int r0p[2] = {rgA * 8, rgA * 8 + 128};
  const int j0 = cg * 64;
  const int tid = threadIdx.x;
  const int lane = tid & 63, wv = tid >> 6;
  const int rc = lane & 15, kg = lane >> 4;
  const int mycol = j0 + wv * 16 + rc;
  const bool act = (kg < 2);           // lane owns rows r0+kg*4..+3

  unsigned* flbase = (unsigned*)(ws + WS_CNT);
  unsigned* flp[2] = {flbase + rgA * (NTEAM * 16),
                      flbase + (rgA + 16) * (NTEAM * 16)};
  // slot-parity ping-pong: slot q reads hb[q&1], writes hb[(q+1)&1]
  _Float16* hb[2] = {(_Float16*)(ws + WS_HB0), (_Float16*)(ws + WS_WM)};

  // --- prologue: Wc (fp16 in ws) and W2 (fp32 global) -> LDS planes ---
  {
    const int col = tid >> 2;          // 0..63
    const int part = tid & 3;          // 0..3, 16 granules each
    const half8* s1 = (const half8*)((const _Float16*)(ws + WS_WC)
                                     + (size_t)(j0 + col) * NN) + part * 16;
    const float* s2 = W2g + (size_t)(j0 + col) * NN + part * 128;
    half8* d1 = (half8*)wc;
    half8* d2 = (half8*)w2;
    const int key = col & 7;
#pragma unroll
    for (int i = 0; i < 16; ++i) {
      int g = part * 16 + i;
      int idx = col * 64 + (g ^ key);
      d1[idx] = s1[i];
      half8 hv;
#pragma unroll
      for (int e = 0; e < 8; ++e) hv[e] = (_Float16)s2[i * 8 + e];
      d2[idx] = hv;
    }
  }
  const float b1s = b1[mycol], b2s = b2[mycol];
  const float c_own = ws[WS_C + mycol];

  // latch both chains' state; store h1(t=0) fp16 into hb[0]; flags = 1
  float xb[2][4], yb[2][4], H[2][4];
  if (act) {
#pragma unroll
    for (int p = 0; p < 2; ++p)
#pragma unroll
      for (int r = 0; r < 4; ++r) {
        int row = r0p[p] + kg * 4 + r;
        xb[p][r] = sysld_f1(ws + WS_X0 + (size_t)row * NN + mycol);
        yb[p][r] = x_init[(size_t)row * NN + mycol];
        float h = tanhf(xb[p][r] + b1s);
        H[p][r] = h;
        sysst_h(hb[0] + (size_t)row * NN + mycol, h);
      }
  }
  __syncthreads();   // drain vmcnt -> h1 MALL-visible
  if (tid == 0) {
    __hip_atomic_store(flp[0] + cg * 16, 1u, __ATOMIC_RELAXED,
                       __HIP_MEMORY_SCOPE_SYSTEM);
    __hip_atomic_store(flp[1] + cg * 16, 1u, __ATOMIC_RELAXED,
                       __HIP_MEMORY_SCOPE_SYSTEM);
  }

  float res[4], res2[4];

  for (int t = 0; t < NT - 1; ++t) {
    const float dt = tspan[t + 1] - tspan[t];
    const float c6 = dt / 6.0f;
#pragma unroll 1
    for (int s = 0; s < 4; ++s) {
      const int q = t * 4 + s;
      const unsigned target = (unsigned)(q + 1);
      const _Float16* rdb = hb[q & 1];
      _Float16* wrb = hb[(q + 1) & 1];
#pragma unroll
      for (int p = 0; p < 2; ++p) {      // two INDEPENDENT teams
        _Float16* pl = p ? plB : plA;
        team_wait(flp[p], target);
        stage8h(pl, rdb + (size_t)r0p[p] * NN, tid);
        __syncthreads();
        gemm8(pl, wc, rc, kg, wv, res);
        if (s == 3) gemm8(pl, w2, rc, kg, wv, res2);
        if (act) {
          if (s < 3) {
            const float a = (s == 2) ? dt : dt * 0.5f;
#pragma unroll
            for (int r = 0; r < 4; ++r) {
              float xs = xb[p][r] + a * (res[r] + c_own);
              float h = tanhf(xs + b1s);
              float st;
              if (s == 2) { H[p][r] += h;       st = H[p][r]; }  // exchange H
              else        { H[p][r] += 2.f * h; st = h;       }  // exchange h
              sysst_h(wrb + (size_t)(r0p[p] + kg * 4 + r) * NN + mycol, st);
            }
          } else {
#pragma unroll
            for (int r = 0; r < 4; ++r) {
              int row = r0p[p] + kg * 4 + r;
              xb[p][r] += c6 * res[r] + dt * c_own;
              yb[p][r] += c6 * res2[r] + dt * b2s;
              out[((size_t)row * NT + (t + 1)) * NN + mycol] = yb[p][r];
              float h = tanhf(xb[p][r] + b1s);   // h1 of step t+1
              H[p][r] = h;
              sysst_h(wrb + (size_t)row * NN + mycol, h);
            }
          }
        }
        team_release(flp[p], cg, target + 1);
      }
    }
  }
}

extern "C" void kernel_launch(void* const* d_in, const int* in_sizes, int n_in,
                              void* d_out, int out_size, void* d_ws, size_t ws_size,
                              hipStream_t stream) {
  const float* x_init = (const float*)d_in[0];
  const float* tspan  = (const float*)d_in[1];
  const float* W1     = (const float*)d_in[2];
  const float* b1     = (const float*)d_in[3];
  const float* W2     = (const float*)d_in[4];
  const float* b2     = (const float*)d_in[5];
  const float* mask   = (const float*)d_in[6];
  float* out = (float*)d_out;
  float* ws  = (float*)d_ws;

  hipLaunchKernelGGL(k_init, dim3(256), dim3(256), 0, stream,
                     W1, mask, x_init, ws, out);
  hipLaunchKernelGGL(k_prep, dim3(512), dim3(128), 0, stream,
                     W2, b2, x_init, ws);

  const unsigned ldsBytes = 144 * 1024;  // wc 64K + w2 64K + plA 8K + plB 8K
  (void)hipFuncSetAttribute((const void*)k_ode,
                            hipFuncAttributeMaxDynamicSharedMemorySize,
                            (int)ldsBytes);

  // 128 blocks x 144KB = 1 block/CU on 128 CUs; all co-resident. Each block
  // serves TWO independent teams (rows rgA*8 and rgA*8+128): chain A's
  // flag/stage MALL round-trip hides under chain B's full compute slot and
  // vice versa — no shared data between chains (round-12 failure mode absent).
  hipLaunchKernelGGL(k_ode, dim3(128), dim3(TPB), ldsBytes, stream,
                     tspan, W2, b1, b2, ws, out, x_init);
}

// Round 14
// 2924.838 us; speedup vs baseline: 1.2533x; 1.0619x over previous
//
#include <hip/hip_runtime.h>
#include <math.h>

#define NN 512      // nodes
#define NB 256      // batch
#define NT 200      // time steps
#define TPB 256
#define NTEAM 8     // blocks per team (64 cols each)

typedef unsigned long long u64;
typedef _Float16 half8 __attribute__((ext_vector_type(8)));
typedef float f32x4 __attribute__((ext_vector_type(4)));

// ws layout (float offsets)
#define WS_WM  0                        // Wm fp32 [NN*NN]; later hb16[1] overlay
#define WS_WC  (NN*NN)                  // Wc fp16 [NN*NN halves]
#define WS_C   (WS_WC + NN*NN/2)        // c = b2*Wm^T fp32 [NN]
#define WS_X0  (WS_C + NN)              // x0 fp32 [NB*NN]
#define WS_HB0 (WS_X0 + NB*NN)          // hb16[0] fp16 [NB*NN halves]
#define WS_CNT (WS_HB0 + NB*NN/2)       // flags: 32 teams x 8 blk x 16 u32

// ---- MALL-coherent ops via compiler-generated scoped atomics (no asm) ----
__device__ __forceinline__ void sysst_u64(u64* p, u64 v) {
  __hip_atomic_store(p, v, __ATOMIC_RELAXED, __HIP_MEMORY_SCOPE_SYSTEM);
}
__device__ __forceinline__ u64 sysld_u64(const u64* p) {
  return __hip_atomic_load(p, __ATOMIC_RELAXED, __HIP_MEMORY_SCOPE_SYSTEM);
}
__device__ __forceinline__ void sysst_f1(float* p, float v) {
  __hip_atomic_store(p, v, __ATOMIC_RELAXED, __HIP_MEMORY_SCOPE_SYSTEM);
}
__device__ __forceinline__ float sysld_f1(const float* p) {
  return __hip_atomic_load(p, __ATOMIC_RELAXED, __HIP_MEMORY_SCOPE_SYSTEM);
}
__device__ __forceinline__ void sysst_u16(unsigned short* p, unsigned short v) {
  __hip_atomic_store(p, v, __ATOMIC_RELAXED, __HIP_MEMORY_SCOPE_SYSTEM);
}
__device__ __forceinline__ void sysst_h(_Float16* p, float v) {
  union { _Float16 hf; unsigned short us; } cv; cv.hf = (_Float16)v;
  sysst_u16((unsigned short*)p, cv.us);
}

__global__ __launch_bounds__(256)
void k_init(const float* __restrict__ W1, const float* __restrict__ mask,
            const float* __restrict__ x_init, float* __restrict__ ws,
            float* __restrict__ out) {
  int gt = blockIdx.x * 256 + threadIdx.x;
  int stride = gridDim.x * 256;
  for (int i = gt; i < NN * NN; i += stride) ws[WS_WM + i] = W1[i] * mask[i];
  for (int i = gt; i < NB * NN / 2; i += stride) {
    u64 q = ((const u64*)x_init)[i];
    int r = i >> 8, np = i & 255;
    *((u64*)(out + (size_t)r * NT * NN) + np) = q;   // traj[:,0,:]
  }
  if (gt < 32 * NTEAM * 16)
    __hip_atomic_store(((unsigned*)(ws + WS_CNT)) + gt, 0u,
                       __ATOMIC_RELAXED, __HIP_MEMORY_SCOPE_SYSTEM);
}

// One block per node j: Wc[j][:] (fp16), c[j], and x0[:,j] = y0 . Wm[j,:].
__global__ __launch_bounds__(128)
void k_prep(const float* __restrict__ W2g, const float* __restrict__ b2,
            const float* __restrict__ x_init, float* __restrict__ ws) {
  __shared__ float w1row[NN];
  const int j = blockIdx.x;
  const int t = threadIdx.x;
  const float* wm = ws + WS_WM + (size_t)j * NN;
  for (int i = t; i < NN; i += 128) w1row[i] = wm[i];
  __syncthreads();

  f32x4 acc = {0.f, 0.f, 0.f, 0.f};
  for (int m = 0; m < NN; ++m) {
    float w = w1row[m];
    if (w != 0.f)
      acc += w * ((const f32x4*)(W2g + (size_t)m * NN))[t];
  }
  _Float16* wcrow = (_Float16*)(ws + WS_WC) + (size_t)j * NN;
#pragma unroll
  for (int e = 0; e < 4; ++e) wcrow[4 * t + e] = (_Float16)acc[e];

  if (t == 0) {
    float s = 0.f;
    for (int m = 0; m < NN; ++m)
      if (w1row[m] != 0.f) s += b2[m] * w1row[m];
    ws[WS_C + j] = s;
  }

#pragma unroll
  for (int rr = 0; rr < 2; ++rr) {
    int r = t + rr * 128;
    const float* y0 = x_init + (size_t)r * NN;
    float s = 0.f;
    for (int m = 0; m < NN; ++m) {
      float w = w1row[m];
      if (w != 0.f) s = fmaf(y0[m], w, s);
    }
    sysst_f1(ws + WS_X0 + (size_t)r * NN + j, s);
  }
}

// wait: poll 8 per-block flags (own cacheline each) for >= target, then sync
__device__ __forceinline__ void team_wait(unsigned* flagsp, unsigned target) {
  if (threadIdx.x < NTEAM) {
    while (__hip_atomic_load(flagsp + threadIdx.x * 16, __ATOMIC_RELAXED,
                             __HIP_MEMORY_SCOPE_AGENT) < target)
      __builtin_amdgcn_s_sleep(1);
  }
  __syncthreads();
}
// release: sync (drains each wave's vmcnt -> h stores MALL-visible), then flag
__device__ __forceinline__ void team_release(unsigned* flagsp, int cg, unsigned e) {
  __syncthreads();
  if (threadIdx.x == 0)
    __hip_atomic_store(flagsp + cg * 16, e, __ATOMIC_RELAXED,
                       __HIP_MEMORY_SCOPE_SYSTEM);
}

// Async-STAGE split: issue sys loads early (regs), write LDS plane late.
struct St { u64 a0, a1, a2, a3; };
__device__ __forceinline__ St stage_load(const _Float16* __restrict__ src,
                                         int tid) {
  const int row = tid >> 5;        // 0..7
  const int seg = tid & 31;        // 0..31
  const u64* s = (const u64*)(src + (size_t)row * NN) + seg * 4;
  St v;
  v.a0 = sysld_u64(s);     v.a1 = sysld_u64(s + 1);
  v.a2 = sysld_u64(s + 2); v.a3 = sysld_u64(s + 3);
  return v;
}
__device__ __forceinline__ void stage_write(_Float16* __restrict__ plane,
                                            const St& v, int tid) {
  const int row = tid >> 5;
  const int seg = tid & 31;
  union { u64 q[2]; half8 h; } u0, u1;
  u0.q[0] = v.a0; u0.q[1] = v.a1; u1.q[0] = v.a2; u1.q[1] = v.a3;
  ((half8*)plane)[row * 64 + ((seg * 2) ^ row)] = u0.h;
  ((half8*)plane)[row * 64 + ((seg * 2 + 1) ^ row)] = u1.h;
}

// Full-K single-pass GEMM, dual accumulators (even/odd kt break dep chain).
__device__ __forceinline__ void gemm8(const _Float16* plane, const _Float16* wb,
                                      int rc, int kg, int wv, float res[4]) {
  const int swz = rc & 7;
  const half8* pA = (const half8*)plane;
  const half8* pB = (const half8*)wb;
  const int abase = (rc & 7) * 64;
  const int bbase = (wv * 16 + rc) * 64;
  f32x4 ae = {0.f, 0.f, 0.f, 0.f};
  f32x4 ao = {0.f, 0.f, 0.f, 0.f};
#pragma unroll
  for (int kt = 0; kt < 16; kt += 2) {
    const int g0 = (kt * 4 + kg) ^ swz;
    const int g1 = ((kt + 1) * 4 + kg) ^ swz;
    ae = __builtin_amdgcn_mfma_f32_16x16x32_f16(pA[abase + g0], pB[bbase + g0],
                                                ae, 0, 0, 0);
    ao = __builtin_amdgcn_mfma_f32_16x16x32_f16(pA[abase + g1], pB[bbase + g1],
                                                ao, 0, 0, 0);
  }
#pragma unroll
  for (int r = 0; r < 4; ++r) res[r] = ae[r] + ao[r];
}

__global__ __launch_bounds__(TPB, 1)
void k_ode(const float* __restrict__ tspan,
           const float* __restrict__ W2g,
           const float* __restrict__ b1,
           const float* __restrict__ b2,
           float* __restrict__ ws,
           float* __restrict__ out,
           const float* __restrict__ x_init) {
  extern __shared__ _Float16 ldsh[];
  _Float16* wc  = ldsh;                // [64 cols][64 granules] 64KB
  _Float16* w2  = ldsh + 32768;        // 64KB
  _Float16* plA = ldsh + 65536;        // [8 rows][64 granules] 8KB
  _Float16* plB = ldsh + 69632;        // 8KB  -> 144KB total

  const int bid = blockIdx.x;          // 0..127
  const int cg = bid & 7, rgA = bid >> 3;   // rgA 0..15; chain B team rgA+16
  const int r0p[2] = {rgA * 8, rgA * 8 + 128};
  const int j0 = cg * 64;
  const int tid = threadIdx.x;
  const int lane = tid & 63, wv = tid >> 6;
  const int rc = lane & 15, kg = lane >> 4;
  const int mycol = j0 + wv * 16 + rc;
  const bool act = (kg < 2);           // lane owns rows r0+kg*4..+3

  unsigned* flbase = (unsigned*)(ws + WS_CNT);
  unsigned* flp[2] = {flbase + rgA * (NTEAM * 16),
                      flbase + (rgA + 16) * (NTEAM * 16)};
  // slot-parity ping-pong: slot q reads hb[q&1], writes hb[(q+1)&1]
  _Float16* hb[2] = {(_Float16*)(ws + WS_HB0), (_Float16*)(ws + WS_WM)};

  // --- prologue: Wc (fp16 in ws) and W2 (fp32 global) -> LDS planes ---
  {
    const int col = tid >> 2;          // 0..63
    const int part = tid & 3;          // 0..3, 16 granules each
    const half8* s1 = (const half8*)((const _Float16*)(ws + WS_WC)
                                     + (size_t)(j0 + col) * NN) + part * 16;
    const float* s2 = W2g + (size_t)(j0 + col) * NN + part * 128;
    half8* d1 = (half8*)wc;
    half8* d2 = (half8*)w2;
    const int key = col & 7;
#pragma unroll
    for (int i = 0; i < 16; ++i) {
      int g = part * 16 + i;
      int idx = col * 64 + (g ^ key);
      d1[idx] = s1[i];
      half8 hv;
#pragma unroll
      for (int e = 0; e < 8; ++e) hv[e] = (_Float16)s2[i * 8 + e];
      d2[idx] = hv;
    }
  }
  const float b1s = b1[mycol], b2s = b2[mycol];
  const float c_own = ws[WS_C + mycol];

  // latch both chains' state; store h1(t=0) fp16 into hb[0]; flags = 1
  float xb[2][4], yb[2][4], H[2][4];
  if (act) {
#pragma unroll
    for (int p = 0; p < 2; ++p)
#pragma unroll
      for (int r = 0; r < 4; ++r) {
        int row = r0p[p] + kg * 4 + r;
        xb[p][r] = sysld_f1(ws + WS_X0 + (size_t)row * NN + mycol);
        yb[p][r] = x_init[(size_t)row * NN + mycol];
        float h = tanhf(xb[p][r] + b1s);
        H[p][r] = h;
        sysst_h(hb[0] + (size_t)row * NN + mycol, h);
      }
  }
  __syncthreads();   // drain vmcnt -> h1 MALL-visible
  if (tid == 0) {
    __hip_atomic_store(flp[0] + cg * 16, 1u, __ATOMIC_RELAXED,
                       __HIP_MEMORY_SCOPE_SYSTEM);
    __hip_atomic_store(flp[1] + cg * 16, 1u, __ATOMIC_RELAXED,
                       __HIP_MEMORY_SCOPE_SYSTEM);
  }

  float res[4], res2[4];

  for (int t = 0; t < NT - 1; ++t) {
    const float dt = tspan[t + 1] - tspan[t];
    const float c6 = dt / 6.0f;
#pragma unroll 1
    for (int s = 0; s < 4; ++s) {
      const int q = t * 4 + s;
      const unsigned target = (unsigned)(q + 1);
      const _Float16* rdb = hb[q & 1];
      _Float16* wrb = hb[(q + 1) & 1];

      // --- issue phase: wait A, launch A loads; wait B, launch B loads ---
      team_wait(flp[0], target);
      St va = stage_load(rdb + (size_t)r0p[0] * NN, tid);
      team_wait(flp[1], target);           // A loads fly during this poll
      St vb = stage_load(rdb + (size_t)r0p[1] * NN, tid);

      // --- chain A slot (B loads fly during gemm A) ---
      stage_write(plA, va, tid);
      __syncthreads();
      gemm8(plA, wc, rc, kg, wv, res);
      if (s == 3) gemm8(plA, w2, rc, kg, wv, res2);
#pragma unroll
      for (int p = 0; p < 1; ++p) {}       // (keep structure flat)
      if (act) {
        if (s < 3) {
          const float a = (s == 2) ? dt : dt * 0.5f;
#pragma unroll
          for (int r = 0; r < 4; ++r) {
            float xs = xb[0][r] + a * (res[r] + c_own);
            float h = tanhf(xs + b1s);
            float st;
            if (s == 2) { H[0][r] += h;       st = H[0][r]; }
            else        { H[0][r] += 2.f * h; st = h;       }
            sysst_h(wrb + (size_t)(r0p[0] + kg * 4 + r) * NN + mycol, st);
          }
        } else {
#pragma unroll
          for (int r = 0; r < 4; ++r) {
            int row = r0p[0] + kg * 4 + r;
            xb[0][r] += c6 * res[r] + dt * c_own;
            yb[0][r] += c6 * res2[r] + dt * b2s;
            out[((size_t)row * NT + (t + 1)) * NN + mycol] = yb[0][r];
            float h = tanhf(xb[0][r] + b1s);
            H[0][r] = h;
            sysst_h(wrb + (size_t)row * NN + mycol, h);
          }
        }
      }
      team_release(flp[0], cg, target + 1);

      // --- chain B slot ---
      stage_write(plB, vb, tid);
      __syncthreads();
      gemm8(plB, wc, rc, kg, wv, res);
      if (s == 3) gemm8(plB, w2, rc, kg, wv, res2);
      if (act) {
        if (s < 3) {
          const float a = (s == 2) ? dt : dt * 0.5f;
#pragma unroll
          for (int r = 0; r < 4; ++r) {
            float xs = xb[1][r] + a * (res[r] + c_own);
            float h = tanhf(xs + b1s);
            float st;
            if (s == 2) { H[1][r] += h;       st = H[1][r]; }
            else        { H[1][r] += 2.f * h; st = h;       }
            sysst_h(wrb + (size_t)(r0p[1] + kg * 4 + r) * NN + mycol, st);
          }
        } else {
#pragma unroll
          for (int r = 0; r < 4; ++r) {
            int row = r0p[1] + kg * 4 + r;
            xb[1][r] += c6 * res[r] + dt * c_own;
            yb[1][r] += c6 * res2[r] + dt * b2s;
            out[((size_t)row * NT + (t + 1)) * NN + mycol] = yb[1][r];
            float h = tanhf(xb[1][r] + b1s);
            H[1][r] = h;
            sysst_h(wrb + (size_t)row * NN + mycol, h);
          }
        }
      }
      team_release(flp[1], cg, target + 1);
    }
  }
}

extern "C" void kernel_launch(void* const* d_in, const int* in_sizes, int n_in,
                              void* d_out, int out_size, void* d_ws, size_t ws_size,
                              hipStream_t stream) {
  const float* x_init = (const float*)d_in[0];
  const float* tspan  = (const float*)d_in[1];
  const float* W1     = (const float*)d_in[2];
  const float* b1     = (const float*)d_in[3];
  const float* W2     = (const float*)d_in[4];
  const float* b2     = (const float*)d_in[5];
  const float* mask   = (const float*)d_in[6];
  float* out = (float*)d_out;
  float* ws  = (float*)d_ws;

  hipLaunchKernelGGL(k_init, dim3(256), dim3(256), 0, stream,
                     W1, mask, x_init, ws, out);
  hipLaunchKernelGGL(k_prep, dim3(512), dim3(128), 0, stream,
                     W2, b2, x_init, ws);

  const unsigned ldsBytes = 144 * 1024;  // wc 64K + w2 64K + plA 8K + plB 8K
  (void)hipFuncSetAttribute((const void*)k_ode,
                            hipFuncAttributeMaxDynamicSharedMemorySize,
                            (int)ldsBytes);

  // 128 blocks x 144KB = 1 block/CU; two independent teams per block.
  // Async-STAGE split: each chain's MALL stage-load RTT flies under the other
  // chain's wait/gemm; flag RTT hidden by the other chain's half-slot (r13).
  hipLaunchKernelGGL(k_ode, dim3(128), dim3(TPB), ldsBytes, stream,
                     tspan, W2, b1, b2, ws, out, x_init);
}

// Round 16
// 2668.342 us; speedup vs baseline: 1.3738x; 1.0961x over previous
//
#include <hip/hip_runtime.h>
#include <math.h>

#define NN 512      // nodes
#define NB 256      // batch
#define NT 200      // time steps
#define TPB 256
#define NTEAM 8     // blocks per team (64 cols each)

typedef unsigned long long u64;
typedef _Float16 half8 __attribute__((ext_vector_type(8)));
typedef float f32x4 __attribute__((ext_vector_type(4)));

// ws layout (float offsets)
#define WS_WM  0                        // Wm fp32 [NN*NN]; later hb16[1] overlay
#define WS_WC  (NN*NN)                  // Wc fp16 [NN*NN halves]
#define WS_C   (WS_WC + NN*NN/2)        // c = b2*Wm^T fp32 [NN]
#define WS_X0  (WS_C + NN)              // x0 fp32 [NB*NN]
#define WS_HB0 (WS_X0 + NB*NN)          // hb16[0] fp16 [NB*NN halves]
#define WS_CNT (WS_HB0 + NB*NN/2)       // flags: 64 teams x 8 blk x 16 u32

// ---- MALL-coherent ops via compiler-generated scoped atomics (no asm) ----
__device__ __forceinline__ void sysst_u64(u64* p, u64 v) {
  __hip_atomic_store(p, v, __ATOMIC_RELAXED, __HIP_MEMORY_SCOPE_SYSTEM);
}
__device__ __forceinline__ u64 sysld_u64(const u64* p) {
  return __hip_atomic_load(p, __ATOMIC_RELAXED, __HIP_MEMORY_SCOPE_SYSTEM);
}
__device__ __forceinline__ void sysst_f1(float* p, float v) {
  __hip_atomic_store(p, v, __ATOMIC_RELAXED, __HIP_MEMORY_SCOPE_SYSTEM);
}
__device__ __forceinline__ float sysld_f1(const float* p) {
  return __hip_atomic_load(p, __ATOMIC_RELAXED, __HIP_MEMORY_SCOPE_SYSTEM);
}
__device__ __forceinline__ void sysst_u16(unsigned short* p, unsigned short v) {
  __hip_atomic_store(p, v, __ATOMIC_RELAXED, __HIP_MEMORY_SCOPE_SYSTEM);
}
__device__ __forceinline__ void sysst_h(_Float16* p, float v) {
  union { _Float16 hf; unsigned short us; } cv; cv.hf = (_Float16)v;
  sysst_u16((unsigned short*)p, cv.us);
}

__global__ __launch_bounds__(256)
void k_init(const float* __restrict__ W1, const float* __restrict__ mask,
            const float* __restrict__ x_init, float* __restrict__ ws,
            float* __restrict__ out) {
  int gt = blockIdx.x * 256 + threadIdx.x;
  int stride = gridDim.x * 256;
  for (int i = gt; i < NN * NN; i += stride) ws[WS_WM + i] = W1[i] * mask[i];
  for (int i = gt; i < NB * NN / 2; i += stride) {
    u64 q = ((const u64*)x_init)[i];
    int r = i >> 8, np = i & 255;
    *((u64*)(out + (size_t)r * NT * NN) + np) = q;   // traj[:,0,:]
  }
  if (gt < 64 * NTEAM * 16)
    __hip_atomic_store(((unsigned*)(ws + WS_CNT)) + gt, 0u,
                       __ATOMIC_RELAXED, __HIP_MEMORY_SCOPE_SYSTEM);
}

// One block per node j: Wc[j][:] (fp16), c[j], and x0[:,j] = y0 . Wm[j,:].
__global__ __launch_bounds__(128)
void k_prep(const float* __restrict__ W2g, const float* __restrict__ b2,
            const float* __restrict__ x_init, float* __restrict__ ws) {
  __shared__ float w1row[NN];
  const int j = blockIdx.x;
  const int t = threadIdx.x;
  const float* wm = ws + WS_WM + (size_t)j * NN;
  for (int i = t; i < NN; i += 128) w1row[i] = wm[i];
  __syncthreads();

  f32x4 acc = {0.f, 0.f, 0.f, 0.f};
  for (int m = 0; m < NN; ++m) {
    float w = w1row[m];
    if (w != 0.f)
      acc += w * ((const f32x4*)(W2g + (size_t)m * NN))[t];
  }
  _Float16* wcrow = (_Float16*)(ws + WS_WC) + (size_t)j * NN;
#pragma unroll
  for (int e = 0; e < 4; ++e) wcrow[4 * t + e] = (_Float16)acc[e];

  if (t == 0) {
    float s = 0.f;
    for (int m = 0; m < NN; ++m)
      if (w1row[m] != 0.f) s += b2[m] * w1row[m];
    ws[WS_C + j] = s;
  }

#pragma unroll
  for (int rr = 0; rr < 2; ++rr) {
    int r = t + rr * 128;
    const float* y0 = x_init + (size_t)r * NN;
    float s = 0.f;
    for (int m = 0; m < NN; ++m) {
      float w = w1row[m];
      if (w != 0.f) s = fmaf(y0[m], w, s);
    }
    sysst_f1(ws + WS_X0 + (size_t)r * NN + j, s);
  }
}

// wait: poll 8 per-block flags (own cacheline each) for >= target, then sync
__device__ __forceinline__ void team_wait(unsigned* flagsp, unsigned target) {
  if (threadIdx.x < NTEAM) {
    while (__hip_atomic_load(flagsp + threadIdx.x * 16, __ATOMIC_RELAXED,
                             __HIP_MEMORY_SCOPE_AGENT) < target)
      __builtin_amdgcn_s_sleep(1);
  }
  __syncthreads();
}
// release: sync (drains each wave's vmcnt -> h stores MALL-visible), then flag
__device__ __forceinline__ void team_release(unsigned* flagsp, int cg, unsigned e) {
  __syncthreads();
  if (threadIdx.x == 0)
    __hip_atomic_store(flagsp + cg * 16, e, __ATOMIC_RELAXED,
                       __HIP_MEMORY_SCOPE_SYSTEM);
}

// Async-STAGE split for a 4-row chain: issue 2 u64 sys loads early, write the
// half8 granule into the LDS plane late. plane = [4 rows][64 granules] = 4KB.
struct St { u64 a0, a1; };
__device__ __forceinline__ St stage_load(const _Float16* __restrict__ src,
                                         int tid) {
  const int row = tid >> 6;        // 0..3 (one row per wave)
  const int g = tid & 63;          // granule
  const u64* s = (const u64*)(src + (size_t)row * NN) + g * 2;
  St v; v.a0 = sysld_u64(s); v.a1 = sysld_u64(s + 1);
  return v;
}
__device__ __forceinline__ void stage_write(_Float16* __restrict__ plane,
                                            const St& v, int tid) {
  const int row = tid >> 6;
  const int g = tid & 63;
  union { u64 q[2]; half8 h; } u; u.q[0] = v.a0; u.q[1] = v.a1;
  ((half8*)plane)[row * 64 + (g ^ row)] = u.h;
}

// Full-K single-pass GEMM, dual accumulators. A-plane key = rc&3 (4 rows,
// lanes rc>=4 duplicate row rc&3); B-plane key = rc&7 (64-col weights,
// written with key col&7). SEPARATE keys — r15's shared-key bug fixed.
__device__ __forceinline__ void gemm8(const _Float16* plane, const _Float16* wb,
                                      int rc, int kg, int wv, float res[4]) {
  const int swzA = rc & 3;
  const int swzB = rc & 7;
  const half8* pA = (const half8*)plane;
  const half8* pB = (const half8*)wb;
  const int abase = (rc & 3) * 64;
  const int bbase = (wv * 16 + rc) * 64;
  f32x4 ae = {0.f, 0.f, 0.f, 0.f};
  f32x4 ao = {0.f, 0.f, 0.f, 0.f};
#pragma unroll
  for (int kt = 0; kt < 16; kt += 2) {
    const int k0 = kt * 4 + kg;
    const int k1 = (kt + 1) * 4 + kg;
    ae = __builtin_amdgcn_mfma_f32_16x16x32_f16(pA[abase + (k0 ^ swzA)],
                                                pB[bbase + (k0 ^ swzB)],
                                                ae, 0, 0, 0);
    ao = __builtin_amdgcn_mfma_f32_16x16x32_f16(pA[abase + (k1 ^ swzA)],
                                                pB[bbase + (k1 ^ swzB)],
                                                ao, 0, 0, 0);
  }
#pragma unroll
  for (int r = 0; r < 4; ++r) res[r] = ae[r] + ao[r];
}

__global__ __launch_bounds__(TPB, 1)
void k_ode(const float* __restrict__ tspan,
           const float* __restrict__ W2g,
           const float* __restrict__ b1,
           const float* __restrict__ b2,
           float* __restrict__ ws,
           float* __restrict__ out,
           const float* __restrict__ x_init) {
  extern __shared__ _Float16 ldsh[];
  _Float16* wc  = ldsh;                // [64 cols][64 granules] 64KB
  _Float16* w2  = ldsh + 32768;        // 64KB
  _Float16* plA = ldsh + 65536;        // [4 rows][64 granules] 4KB
  _Float16* plB = ldsh + 67584;        // 4KB  -> 136KB total

  const int bid = blockIdx.x;          // 0..255
  const int cg = bid & 7, rgA = bid >> 3;   // rgA 0..31; chain B team rgA+32
  const int r0p[2] = {rgA * 4, rgA * 4 + 128};
  const int j0 = cg * 64;
  const int tid = threadIdx.x;
  const int lane = tid & 63, wv = tid >> 6;
  const int rc = lane & 15, kg = lane >> 4;
  const int mycol = j0 + wv * 16 + rc;
  const bool act = (kg == 0);          // lane owns rows r0p[p]+0..3 (col mycol)

  unsigned* flbase = (unsigned*)(ws + WS_CNT);
  unsigned* flp[2] = {flbase + rgA * (NTEAM * 16),
                      flbase + (rgA + 32) * (NTEAM * 16)};
  // slot-parity ping-pong: slot q reads hb[q&1], writes hb[(q+1)&1]
  _Float16* hb[2] = {(_Float16*)(ws + WS_HB0), (_Float16*)(ws + WS_WM)};

  // --- prologue: Wc (fp16 in ws) and W2 (fp32 global) -> LDS planes ---
  {
    const int col = tid >> 2;          // 0..63
    const int part = tid & 3;          // 0..3, 16 granules each
    const half8* s1 = (const half8*)((const _Float16*)(ws + WS_WC)
                                     + (size_t)(j0 + col) * NN) + part * 16;
    const float* s2 = W2g + (size_t)(j0 + col) * NN + part * 128;
    half8* d1 = (half8*)wc;
    half8* d2 = (half8*)w2;
    const int key = col & 7;
#pragma unroll
    for (int i = 0; i < 16; ++i) {
      int g = part * 16 + i;
      int idx = col * 64 + (g ^ key);
      d1[idx] = s1[i];
      half8 hv;
#pragma unroll
      for (int e = 0; e < 8; ++e) hv[e] = (_Float16)s2[i * 8 + e];
      d2[idx] = hv;
    }
  }
  const float b1s = b1[mycol], b2s = b2[mycol];
  const float c_own = ws[WS_C + mycol];

  // latch both chains' state; store h1(t=0) fp16 into hb[0]; flags = 1
  float xb[2][4], yb[2][4], H[2][4];
  if (act) {
#pragma unroll
    for (int p = 0; p < 2; ++p)
#pragma unroll
      for (int r = 0; r < 4; ++r) {
        int row = r0p[p] + r;
        xb[p][r] = sysld_f1(ws + WS_X0 + (size_t)row * NN + mycol);
        yb[p][r] = x_init[(size_t)row * NN + mycol];
        float h = tanhf(xb[p][r] + b1s);
        H[p][r] = h;
        sysst_h(hb[0] + (size_t)row * NN + mycol, h);
      }
  }
  __syncthreads();   // drain vmcnt -> h1 MALL-visible
  if (tid == 0) {
    __hip_atomic_store(flp[0] + cg * 16, 1u, __ATOMIC_RELAXED,
                       __HIP_MEMORY_SCOPE_SYSTEM);
    __hip_atomic_store(flp[1] + cg * 16, 1u, __ATOMIC_RELAXED,
                       __HIP_MEMORY_SCOPE_SYSTEM);
  }

  float res[4], res2[4];

  for (int t = 0; t < NT - 1; ++t) {
    const float dt = tspan[t + 1] - tspan[t];
    const float c6 = dt / 6.0f;
#pragma unroll 1
    for (int s = 0; s < 4; ++s) {
      const int q = t * 4 + s;
      const unsigned target = (unsigned)(q + 1);
      const _Float16* rdb = hb[q & 1];
      _Float16* wrb = hb[(q + 1) & 1];

      // --- issue phase: wait A, launch A loads; wait B, launch B loads ---
      team_wait(flp[0], target);
      St va = stage_load(rdb + (size_t)r0p[0] * NN, tid);
      team_wait(flp[1], target);           // A loads fly during this poll
      St vb = stage_load(rdb + (size_t)r0p[1] * NN, tid);

      // --- chain A slot (B loads fly during gemm A) ---
      stage_write(plA, va, tid);
      __syncthreads();
      gemm8(plA, wc, rc, kg, wv, res);
      if (s == 3) gemm8(plA, w2, rc, kg, wv, res2);
      if (act) {
        if (s < 3) {
          const float a = (s == 2) ? dt : dt * 0.5f;
#pragma unroll
          for (int r = 0; r < 4; ++r) {
            float xs = xb[0][r] + a * (res[r] + c_own);
            float h = tanhf(xs + b1s);
            float st;
            if (s == 2) { H[0][r] += h;       st = H[0][r]; }
            else        { H[0][r] += 2.f * h; st = h;       }
            sysst_h(wrb + (size_t)(r0p[0] + r) * NN + mycol, st);
          }
        } else {
#pragma unroll
          for (int r = 0; r < 4; ++r) {
            int row = r0p[0] + r;
            xb[0][r] += c6 * res[r] + dt * c_own;
            yb[0][r] += c6 * res2[r] + dt * b2s;
            out[((size_t)row * NT + (t + 1)) * NN + mycol] = yb[0][r];
            float h = tanhf(xb[0][r] + b1s);
            H[0][r] = h;
            sysst_h(wrb + (size_t)row * NN + mycol, h);
          }
        }
      }
      team_release(flp[0], cg, target + 1);

      // --- chain B slot ---
      stage_write(plB, vb, tid);
      __syncthreads();
      gemm8(plB, wc, rc, kg, wv, res);
      if (s == 3) gemm8(plB, w2, rc, kg, wv, res2);
      if (act) {
        if (s < 3) {
          const float a = (s == 2) ? dt : dt * 0.5f;
#pragma unroll
          for (int r = 0; r < 4; ++r) {
            float xs = xb[1][r] + a * (res[r] + c_own);
            float h = tanhf(xs + b1s);
            float st;
            if (s == 2) { H[1][r] += h;       st = H[1][r]; }
            else        { H[1][r] += 2.f * h; st = h;       }
            sysst_h(wrb + (size_t)(r0p[1] + r) * NN + mycol, st);
          }
        } else {
#pragma unroll
          for (int r = 0; r < 4; ++r) {
            int row = r0p[1] + r;
            xb[1][r] += c6 * res[r] + dt * c_own;
            yb[1][r] += c6 * res2[r] + dt * b2s;
            out[((size_t)row * NT + (t + 1)) * NN + mycol] = yb[1][r];
            float h = tanhf(xb[1][r] + b1s);
            H[1][r] = h;
            sysst_h(wrb + (size_t)row * NN + mycol, h);
          }
        }
      }
      team_release(flp[1], cg, target + 1);
    }
  }
}

extern "C" void kernel_launch(void* const* d_in, const int* in_sizes, int n_in,
                              void* d_out, int out_size, void* d_ws, size_t ws_size,
                              hipStream_t stream) {
  const float* x_init = (const float*)d_in[0];
  const float* tspan  = (const float*)d_in[1];
  const float* W1     = (const float*)d_in[2];
  const float* b1     = (const float*)d_in[3];
  const float* W2     = (const float*)d_in[4];
  const float* b2     = (const float*)d_in[5];
  const float* mask   = (const float*)d_in[6];
  float* out = (float*)d_out;
  float* ws  = (float*)d_ws;

  hipLaunchKernelGGL(k_init, dim3(256), dim3(256), 0, stream,
                     W1, mask, x_init, ws, out);
  hipLaunchKernelGGL(k_prep, dim3(512), dim3(128), 0, stream,
                     W2, b2, x_init, ws);

  const unsigned ldsBytes = 136 * 1024;  // wc 64K + w2 64K + plA 4K + plB 4K
  (void)hipFuncSetAttribute((const void*)k_ode,
                            hipFuncAttributeMaxDynamicSharedMemorySize,
                            (int)ldsBytes);

  // 256 blocks x 136KB = 1 block/CU on all 256 CUs; two independent 4-row
  // chains per block (64 teams x 8 blocks). Per-slot work halved vs r14;
  // flag RTT and stage RTT each hide under the other chain's half-slot.
  hipLaunchKernelGGL(k_ode, dim3(256), dim3(TPB), ldsBytes, stream,
                     tspan, W2, b1, b2, ws, out, x_init);
}